// Round 3
// baseline (350.431 us; speedup 1.0000x reference)
//
#include <hip/hip_runtime.h>
#include <cstdint>
#include <cstddef>

#define N 4096
#define M 4096
#define DT 0.01f

#define BM 128
#define BN 128
#define BK 32
#define JSPLIT 3072   // rows >= JSPLIT use split-K + atomics; below: owned tiles

typedef short bf16x8 __attribute__((ext_vector_type(8)));
typedef float f32x4 __attribute__((ext_vector_type(4)));

__device__ __forceinline__ unsigned short f2bf(float f) {
  unsigned u = __builtin_bit_cast(unsigned, f);
  return (unsigned short)((u + 0x7fffu + ((u >> 16) & 1u)) >> 16);  // RNE
}
__device__ __forceinline__ float bf2f(unsigned short b) {
  return __builtin_bit_cast(float, (unsigned)b << 16);
}
__device__ __forceinline__ void atomAddF(float* p, float v) {
  unsafeAtomicAdd(p, v);  // global_atomic_add_f32, no-return
}

// kbT[i*N + l] = bf16(exp(-x[l*M+i]))  (transposed, K-contiguous B-operand)
// For l >= JSPLIT only: out[l*M+i] = fe[l] + DT*(0.5*k0[i]*h[l] - 0.5*k[l,i]*h[0])
// (split-K gemm blocks atomic-add -DT*partial on top; owned tiles write out fully).
__global__ __launch_bounds__(256)
void exp_tr_init_kernel(const float* __restrict__ x, const float* __restrict__ fe,
                        const float* __restrict__ h, unsigned short* __restrict__ kbT,
                        float* __restrict__ out) {
  __shared__ __align__(16) unsigned short tileT[64][72];  // [i][l]
  const int i0 = blockIdx.x * 64, l0 = blockIdx.y * 64;
  const int tid = threadIdx.x;
  const int ci = (tid & 15) * 4;
  const int r0 = tid >> 4;
  const float h0 = h[0];
  const float4 x0v = *reinterpret_cast<const float4*>(&x[i0 + ci]);
  const float k00 = expf(-x0v.x), k01 = expf(-x0v.y),
              k02 = expf(-x0v.z), k03 = expf(-x0v.w);
#pragma unroll
  for (int rr = 0; rr < 4; ++rr) {
    const int l = l0 + r0 + rr * 16;
    const float4 xv = *reinterpret_cast<const float4*>(&x[(size_t)l * M + i0 + ci]);
    const float kb0 = expf(-xv.x), kb1 = expf(-xv.y),
                kb2 = expf(-xv.z), kb3 = expf(-xv.w);
    if (l >= JSPLIT) {
      const float hj = h[l], fj = fe[l];
      float4 o;
      o.x = fj + DT * (0.5f * k00 * hj - 0.5f * kb0 * h0);
      o.y = fj + DT * (0.5f * k01 * hj - 0.5f * kb1 * h0);
      o.z = fj + DT * (0.5f * k02 * hj - 0.5f * kb2 * h0);
      o.w = fj + DT * (0.5f * k03 * hj - 0.5f * kb3 * h0);
      *reinterpret_cast<float4*>(&out[(size_t)l * M + i0 + ci]) = o;
    }
    const int lr = r0 + rr * 16;
    tileT[ci + 0][lr] = f2bf(kb0);
    tileT[ci + 1][lr] = f2bf(kb1);
    tileT[ci + 2][lr] = f2bf(kb2);
    tileT[ci + 3][lr] = f2bf(kb3);
  }
  __syncthreads();
  const int ir = tid >> 2, cc = tid & 3;
#pragma unroll
  for (int s = 0; s < 2; ++s) {
    const int ch = cc + s * 4;
    bf16x8 v = *reinterpret_cast<const bf16x8*>(&tileT[ir][ch * 8]);
    *reinterpret_cast<bf16x8*>(&kbT[(size_t)(i0 + ir) * N + l0 + ch * 8]) = v;
  }
}

// T[j*N + l] = bf16(h[j-l]) for l<=j else 0
__global__ void build_T_kernel(const float* __restrict__ h,
                               unsigned short* __restrict__ T) {
  const int j = blockIdx.y;
  const int l0 = (blockIdx.x * blockDim.x + threadIdx.x) * 8;
  unsigned short v[8];
#pragma unroll
  for (int s = 0; s < 8; ++s) {
    int l = l0 + s;
    float hv = (l <= j) ? h[j - l] : 0.0f;
    v[s] = f2bf(hv);
  }
  uint4 pack;
  pack.x = (unsigned)v[0] | ((unsigned)v[1] << 16);
  pack.y = (unsigned)v[2] | ((unsigned)v[3] << 16);
  pack.z = (unsigned)v[4] | ((unsigned)v[5] << 16);
  pack.w = (unsigned)v[6] | ((unsigned)v[7] << 16);
  *reinterpret_cast<uint4*>(&T[(size_t)j * N + l0]) = pack;
}

__device__ __forceinline__ void gld16(void* lds, const void* g) {
  __builtin_amdgcn_global_load_lds(
      (const __attribute__((address_space(1))) void*)g,
      (__attribute__((address_space(3))) void*)lds, 16, 0, 0);
}

// Triangular GEMM, 40 y-units x 32 col-blocks, heavy-first:
//   uy  0..7  : by=31-uy,      K-chunk [0,64)          -> atomicAdd partial
//   uy  8..15 : by=31-(uy-8),  K-chunk [64, 4*by+4)    -> atomicAdd partial
//   uy 16..39 : by=23-(uy-16), full K [0, 4*by+4)      -> owned, fused affine, plain store
__global__ __launch_bounds__(256)
void gemm_tri_kernel(const unsigned short* __restrict__ Tm,
                     const unsigned short* __restrict__ Bt,
                     const float* __restrict__ fe,
                     const float* __restrict__ h,
                     float* __restrict__ out) {
  __shared__ __align__(16) unsigned short As[BM * BK];  // [row j][k], 64B rows
  __shared__ __align__(16) unsigned short Bs[BN * BK];  // [row i][k], 64B rows

  const int tid = threadIdx.x;
  const int wave = tid >> 6, lane = tid & 63;
  const int wr = wave >> 1, wc = wave & 1;
  const int lo16 = lane & 15, hi4 = lane >> 4;
  const int i0 = blockIdx.x * BN;

  const int uy = (int)blockIdx.y;
  int by, t0, t1, owned;
  if (uy < 8)       { by = 31 - uy;        t0 = 0;  t1 = 64;          owned = 0; }
  else if (uy < 16) { by = 31 - (uy - 8);  t0 = 64; t1 = 4 * by + 4;  owned = 0; }
  else              { by = 23 - (uy - 16); t0 = 0;  t1 = 4 * by + 4;  owned = 1; }
  const int j0 = by * BM;

  f32x4 acc[4][4] = {};

  const int row0 = tid >> 2;
  const int cb = (tid & 3) * 16;
  const size_t strideB = (size_t)N * 2;

  for (int t = t0; t < t1; ++t) {
    const int l0 = t * BK;
    const char* Abase = (const char*)Tm + (size_t)j0 * strideB + (size_t)l0 * 2;
    const char* Bbase = (const char*)Bt + (size_t)i0 * strideB + (size_t)l0 * 2;
    char* AsB = (char*)As;
    char* BsB = (char*)Bs;
    gld16(AsB + wave * 1024,        Abase + (size_t)row0 * strideB + cb);
    gld16(AsB + 4096 + wave * 1024, Abase + (size_t)(row0 + 64) * strideB + cb);
    gld16(BsB + wave * 1024,        Bbase + (size_t)row0 * strideB + cb);
    gld16(BsB + 4096 + wave * 1024, Bbase + (size_t)(row0 + 64) * strideB + cb);
    __syncthreads();

    bf16x8 af[4], bfr[4];
#pragma unroll
    for (int mt = 0; mt < 4; ++mt) {
      int row = wr * 64 + mt * 16 + lo16;
      af[mt] = *reinterpret_cast<const bf16x8*>((const char*)As + row * 64 + hi4 * 16);
    }
#pragma unroll
    for (int nt = 0; nt < 4; ++nt) {
      int row = wc * 64 + nt * 16 + lo16;
      bfr[nt] = *reinterpret_cast<const bf16x8*>((const char*)Bs + row * 64 + hi4 * 16);
    }
#pragma unroll
    for (int mt = 0; mt < 4; ++mt) {
#pragma unroll
      for (int nt = 0; nt < 4; ++nt) {
        acc[mt][nt] = __builtin_amdgcn_mfma_f32_16x16x32_bf16(
            af[mt], bfr[nt], acc[mt][nt], 0, 0, 0);
      }
    }
    __syncthreads();
  }

  if (owned) {
    // Fused affine epilogue; k[j,i] from bf16 kbT (error ~1e-5, negligible).
    const float h0 = h[0];
#pragma unroll
    for (int nt = 0; nt < 4; ++nt) {
      const int i = i0 + wc * 64 + nt * 16 + lo16;
      const unsigned short* krow = &Bt[(size_t)i * N];
      const float k0i = bf2f(krow[0]);
#pragma unroll
      for (int mt = 0; mt < 4; ++mt) {
        const int jb = j0 + wr * 64 + mt * 16 + hi4 * 4;
        ushort4 kv = *reinterpret_cast<const ushort4*>(&krow[jb]);
        const unsigned short kk[4] = {kv.x, kv.y, kv.z, kv.w};
#pragma unroll
        for (int r = 0; r < 4; ++r) {
          const int j = jb + r;
          out[(size_t)j * M + i] =
              fe[j] + DT * (0.5f * k0i * h[j] - 0.5f * bf2f(kk[r]) * h0 - acc[mt][nt][r]);
        }
      }
    }
  } else {
#pragma unroll
    for (int nt = 0; nt < 4; ++nt) {
      const int i = i0 + wc * 64 + nt * 16 + lo16;
#pragma unroll
      for (int mt = 0; mt < 4; ++mt) {
#pragma unroll
        for (int r = 0; r < 4; ++r) {
          const int j = j0 + wr * 64 + mt * 16 + hi4 * 4 + r;
          atomAddF(&out[(size_t)j * M + i], -DT * acc[mt][nt][r]);
        }
      }
    }
  }
}

extern "C" void kernel_launch(void* const* d_in, const int* in_sizes, int n_in,
                              void* d_out, int out_size, void* d_ws, size_t ws_size,
                              hipStream_t stream) {
  const float* x  = (const float*)d_in[0];
  const float* fe = (const float*)d_in[1];
  const float* h  = (const float*)d_in[2];
  float* out = (float*)d_out;

  const size_t matBytes = (size_t)N * N * sizeof(unsigned short);  // 32 MiB
  if (ws_size < 2 * matBytes) return;

  unsigned short* kbT = (unsigned short*)d_ws;
  unsigned short* Tm  = (unsigned short*)((char*)d_ws + matBytes);

  exp_tr_init_kernel<<<dim3(M / 64, N / 64), 256, 0, stream>>>(x, fe, h, kbT, out);
  build_T_kernel<<<dim3(2, N), 256, 0, stream>>>(h, Tm);
  gemm_tri_kernel<<<dim3(M / BN, 40), 256, 0, stream>>>(Tm, kbT, fe, h, out);
}

// Round 4
// 315.473 us; speedup vs baseline: 1.1108x; 1.1108x over previous
//
#include <hip/hip_runtime.h>
#include <cstdint>
#include <cstddef>

#define N 4096
#define M 4096
#define DT 0.01f

#define BM 128
#define BN 128
#define BK 32

typedef short bf16x8 __attribute__((ext_vector_type(8)));
typedef float f32x4 __attribute__((ext_vector_type(4)));

__device__ __forceinline__ unsigned short f2bf(float f) {
  unsigned u = __builtin_bit_cast(unsigned, f);
  return (unsigned short)((u + 0x7fffu + ((u >> 16) & 1u)) >> 16);  // RNE
}
__device__ __forceinline__ void atomAddF(float* p, float v) {
  unsafeAtomicAdd(p, v);  // global_atomic_add_f32, no-return
}

// kbT[i*N + l] = bf16(exp(-x[l*M+i]))  (transposed -> K-contiguous GEMM B-operand)
__global__ __launch_bounds__(256)
void exp_tr_kernel(const float* __restrict__ x, unsigned short* __restrict__ kbT) {
  __shared__ __align__(16) unsigned short tileT[64][72];  // [i][l]
  const int i0 = blockIdx.x * 64, l0 = blockIdx.y * 64;
  const int tid = threadIdx.x;
  const int ci = (tid & 15) * 4;
  const int r0 = tid >> 4;
#pragma unroll
  for (int rr = 0; rr < 4; ++rr) {
    const int l = l0 + r0 + rr * 16;
    const float4 xv = *reinterpret_cast<const float4*>(&x[(size_t)l * M + i0 + ci]);
    const int lr = r0 + rr * 16;
    tileT[ci + 0][lr] = f2bf(__expf(-xv.x));
    tileT[ci + 1][lr] = f2bf(__expf(-xv.y));
    tileT[ci + 2][lr] = f2bf(__expf(-xv.z));
    tileT[ci + 3][lr] = f2bf(__expf(-xv.w));
  }
  __syncthreads();
  const int ir = tid >> 2, cc = tid & 3;
#pragma unroll
  for (int s = 0; s < 2; ++s) {
    const int ch = cc + s * 4;
    bf16x8 v = *reinterpret_cast<const bf16x8*>(&tileT[ir][ch * 8]);
    *reinterpret_cast<bf16x8*>(&kbT[(size_t)(i0 + ir) * N + l0 + ch * 8]) = v;
  }
}

// Weighted Toeplitz: T'[j,l] = w * h[j-l] for l<=j (else 0),
// w = 1 + 0.5*[l==j] - 0.5*[l==0]. Folds the reference's entire affine term:
// out = fe[j] - dt * (T' @ k)[j,i].
__global__ void build_T_kernel(const float* __restrict__ h,
                               unsigned short* __restrict__ T) {
  const int j = blockIdx.y;
  const int l0 = (blockIdx.x * blockDim.x + threadIdx.x) * 8;
  unsigned short v[8];
#pragma unroll
  for (int s = 0; s < 8; ++s) {
    const int l = l0 + s;
    float val = 0.0f;
    if (l <= j) {
      const float w = (l == j ? 1.5f : 1.0f) - (l == 0 ? 0.5f : 0.0f);
      val = w * h[j - l];
    }
    v[s] = f2bf(val);
  }
  uint4 pack;
  pack.x = (unsigned)v[0] | ((unsigned)v[1] << 16);
  pack.y = (unsigned)v[2] | ((unsigned)v[3] << 16);
  pack.z = (unsigned)v[4] | ((unsigned)v[5] << 16);
  pack.w = (unsigned)v[6] | ((unsigned)v[7] << 16);
  *reinterpret_cast<uint4*>(&T[(size_t)j * N + l0]) = pack;
}

// out[j,i] = fe[j]  (baseline; gemm chunks atomic-add the -dt*conv term)
__global__ void fill_fe_kernel(const float* __restrict__ fe, float* __restrict__ out) {
  const int j = blockIdx.y;
  const float vj = fe[j];
  const float4 o = {vj, vj, vj, vj};
  const int i = (blockIdx.x * 256 + threadIdx.x) * 4;
  *reinterpret_cast<float4*>(&out[(size_t)j * M + i]) = o;
}

__device__ __forceinline__ void gld16(void* lds, const void* g) {
  __builtin_amdgcn_global_load_lds(
      (const __attribute__((address_space(1))) void*)g,
      (__attribute__((address_space(3))) void*)lds, 16, 0, 0);
}

// Triangular GEMM, uniform split-K chunks (<=32 BK-iters), all-atomic epilogue.
// 80 y-units/col: row-block by has ceil((by+1)/8) chunks; heavy chunks dispatch first.
__global__ __launch_bounds__(256)
void gemm_tri_kernel(const unsigned short* __restrict__ Tm,
                     const unsigned short* __restrict__ Bt,
                     float* __restrict__ out) {
  __shared__ __align__(16) unsigned short As[BM * BK];  // [row j][k], 64B rows
  __shared__ __align__(16) unsigned short Bs[BN * BK];  // [row i][k], 64B rows

  const int tid = threadIdx.x;
  const int wave = tid >> 6, lane = tid & 63;
  const int wr = wave >> 1, wc = wave & 1;
  const int lo16 = lane & 15, hi4 = lane >> 4;
  const int i0 = blockIdx.x * BN;

  // unit decode: ur in [0,80); reversed so 32-iter chunks of heavy rows go first
  const int ur = 79 - (int)blockIdx.y;
  int by, c;
  if (ur < 8)       { by = ur;                        c = 0; }
  else if (ur < 24) { const int q = ur - 8;  by = 8  + (q >> 1); c = q & 1; }
  else if (ur < 48) { const int q = ur - 24; const int d = q / 3; by = 16 + d; c = q - 3 * d; }
  else              { const int q = ur - 48; by = 24 + (q >> 2); c = q & 3; }
  const int t0 = c * 32;
  const int full = 4 * by + 4;
  const int t1 = (t0 + 32 < full) ? t0 + 32 : full;
  const int j0 = by * BM;

  f32x4 acc[4][4] = {};

  const int row0 = tid >> 2;
  const int cb = (tid & 3) * 16;
  const size_t strideB = (size_t)N * 2;

  for (int t = t0; t < t1; ++t) {
    const int l0 = t * BK;
    const char* Abase = (const char*)Tm + (size_t)j0 * strideB + (size_t)l0 * 2;
    const char* Bbase = (const char*)Bt + (size_t)i0 * strideB + (size_t)l0 * 2;
    char* AsB = (char*)As;
    char* BsB = (char*)Bs;
    gld16(AsB + wave * 1024,        Abase + (size_t)row0 * strideB + cb);
    gld16(AsB + 4096 + wave * 1024, Abase + (size_t)(row0 + 64) * strideB + cb);
    gld16(BsB + wave * 1024,        Bbase + (size_t)row0 * strideB + cb);
    gld16(BsB + 4096 + wave * 1024, Bbase + (size_t)(row0 + 64) * strideB + cb);
    __syncthreads();

    bf16x8 af[4], bfr[4];
#pragma unroll
    for (int mt = 0; mt < 4; ++mt) {
      int row = wr * 64 + mt * 16 + lo16;
      af[mt] = *reinterpret_cast<const bf16x8*>((const char*)As + row * 64 + hi4 * 16);
    }
#pragma unroll
    for (int nt = 0; nt < 4; ++nt) {
      int row = wc * 64 + nt * 16 + lo16;
      bfr[nt] = *reinterpret_cast<const bf16x8*>((const char*)Bs + row * 64 + hi4 * 16);
    }
#pragma unroll
    for (int mt = 0; mt < 4; ++mt) {
#pragma unroll
      for (int nt = 0; nt < 4; ++nt) {
        acc[mt][nt] = __builtin_amdgcn_mfma_f32_16x16x32_bf16(
            af[mt], bfr[nt], acc[mt][nt], 0, 0, 0);
      }
    }
    __syncthreads();
  }

  // Minimal epilogue (keeps VGPR ~76): out -= DT * partial, atomically.
#pragma unroll
  for (int nt = 0; nt < 4; ++nt) {
    const int i = i0 + wc * 64 + nt * 16 + lo16;
#pragma unroll
    for (int mt = 0; mt < 4; ++mt) {
#pragma unroll
      for (int r = 0; r < 4; ++r) {
        const int j = j0 + wr * 64 + mt * 16 + hi4 * 4 + r;
        atomAddF(&out[(size_t)j * M + i], -DT * acc[mt][nt][r]);
      }
    }
  }
}

extern "C" void kernel_launch(void* const* d_in, const int* in_sizes, int n_in,
                              void* d_out, int out_size, void* d_ws, size_t ws_size,
                              hipStream_t stream) {
  const float* x  = (const float*)d_in[0];
  const float* fe = (const float*)d_in[1];
  const float* h  = (const float*)d_in[2];
  float* out = (float*)d_out;

  const size_t matBytes = (size_t)N * N * sizeof(unsigned short);  // 32 MiB
  if (ws_size < 2 * matBytes) return;

  unsigned short* kbT = (unsigned short*)d_ws;
  unsigned short* Tm  = (unsigned short*)((char*)d_ws + matBytes);

  exp_tr_kernel<<<dim3(M / 64, N / 64), 256, 0, stream>>>(x, kbT);
  build_T_kernel<<<dim3(2, N), 256, 0, stream>>>(h, Tm);
  fill_fe_kernel<<<dim3(M / 1024, N), 256, 0, stream>>>(fe, out);
  gemm_tri_kernel<<<dim3(M / BN, 80), 256, 0, stream>>>(Tm, kbT, out);
}

// Round 5
// 248.430 us; speedup vs baseline: 1.4106x; 1.2699x over previous
//
#include <hip/hip_runtime.h>
#include <cstdint>
#include <cstddef>

#define N 4096
#define M 4096
#define DT 0.01f

#define BM 128
#define BN 128
#define BK 32

typedef short bf16x8 __attribute__((ext_vector_type(8)));
typedef float f32x4 __attribute__((ext_vector_type(4)));

__device__ __forceinline__ unsigned short f2bf(float f) {
  unsigned u = __builtin_bit_cast(unsigned, f);
  return (unsigned short)((u + 0x7fffu + ((u >> 16) & 1u)) >> 16);  // RNE
}

// kbT[i*N + l] = bf16(exp(-x[l*M+i]))  (transposed -> K-contiguous GEMM B-operand)
// Pad 66 (row = 132B): write banks 2-way (free per m136), b128 reads 2-way.
__global__ __launch_bounds__(256)
void exp_tr_kernel(const float* __restrict__ x, unsigned short* __restrict__ kbT) {
  __shared__ __align__(16) unsigned short tileT[64][66];  // [i][l]
  const int i0 = blockIdx.x * 64, l0 = blockIdx.y * 64;
  const int tid = threadIdx.x;
  const int ci = (tid & 15) * 4;
  const int r0 = tid >> 4;
#pragma unroll
  for (int rr = 0; rr < 4; ++rr) {
    const int l = l0 + r0 + rr * 16;
    const float4 xv = *reinterpret_cast<const float4*>(&x[(size_t)l * M + i0 + ci]);
    const int lr = r0 + rr * 16;
    tileT[ci + 0][lr] = f2bf(__expf(-xv.x));
    tileT[ci + 1][lr] = f2bf(__expf(-xv.y));
    tileT[ci + 2][lr] = f2bf(__expf(-xv.z));
    tileT[ci + 3][lr] = f2bf(__expf(-xv.w));
  }
  __syncthreads();
  const int ir = tid >> 2, cc = tid & 3;
#pragma unroll
  for (int s = 0; s < 2; ++s) {
    const int ch = cc + s * 4;
    bf16x8 v = *reinterpret_cast<const bf16x8*>(&tileT[ir][ch * 8]);
    *reinterpret_cast<bf16x8*>(&kbT[(size_t)(i0 + ir) * N + l0 + ch * 8]) = v;
  }
}

// Weighted Toeplitz: T'[j,l] = w * h[j-l] for l<=j (else 0),
// w = 1 + 0.5*[l==j] - 0.5*[l==0]  =>  out = fe[j] - dt * (T' @ k)[j,i].
__global__ void build_T_kernel(const float* __restrict__ h,
                               unsigned short* __restrict__ T) {
  const int j = blockIdx.y;
  const int l0 = (blockIdx.x * blockDim.x + threadIdx.x) * 8;
  unsigned short v[8];
#pragma unroll
  for (int s = 0; s < 8; ++s) {
    const int l = l0 + s;
    float val = 0.0f;
    if (l <= j) {
      const float w = (l == j ? 1.5f : 1.0f) - (l == 0 ? 0.5f : 0.0f);
      val = w * h[j - l];
    }
    v[s] = f2bf(val);
  }
  uint4 pack;
  pack.x = (unsigned)v[0] | ((unsigned)v[1] << 16);
  pack.y = (unsigned)v[2] | ((unsigned)v[3] << 16);
  pack.z = (unsigned)v[4] | ((unsigned)v[5] << 16);
  pack.w = (unsigned)v[6] | ((unsigned)v[7] << 16);
  *reinterpret_cast<uint4*>(&T[(size_t)j * N + l0]) = pack;
}

__device__ __forceinline__ void gld16(void* lds, const void* g) {
  __builtin_amdgcn_global_load_lds(
      (const __attribute__((address_space(1))) void*)g,
      (__attribute__((address_space(3))) void*)lds, 16, 0, 0);
}

// Paired triangular GEMM: block (bx, p) owns BOTH row-blocks p and 31-p for
// col-block bx, processed sequentially. Iter counts 4(p+1) + 4(32-p) = 132
// for every block -> perfectly uniform grid of 512 owned tiles pairs.
// No atomics, no init pass: epilogue writes out = fe[j] - DT*acc directly.
__global__ __launch_bounds__(256)
void gemm_tri_kernel(const unsigned short* __restrict__ Tm,
                     const unsigned short* __restrict__ Bt,
                     const float* __restrict__ fe,
                     float* __restrict__ out) {
  __shared__ __align__(16) unsigned short As[BM * BK];  // [row j][k], 64B rows
  __shared__ __align__(16) unsigned short Bs[BN * BK];  // [row i][k], 64B rows

  const int tid = threadIdx.x;
  const int wave = tid >> 6, lane = tid & 63;
  const int wr = wave >> 1, wc = wave & 1;
  const int lo16 = lane & 15, hi4 = lane >> 4;
  const int i0 = blockIdx.x * BN;
  const int p = (int)blockIdx.y;

  const int row0 = tid >> 2;
  const int cb = (tid & 3) * 16;
  const size_t strideB = (size_t)N * 2;

#pragma unroll 1
  for (int ph = 0; ph < 2; ++ph) {
    const int by = ph ? (31 - p) : p;
    const int j0 = by * BM;
    const int nIter = 4 * by + 4;  // causal K bound for this row block

    f32x4 acc[4][4] = {};

#pragma unroll 1
    for (int t = 0; t < nIter; ++t) {
      const int l0 = t * BK;
      const char* Abase = (const char*)Tm + (size_t)j0 * strideB + (size_t)l0 * 2;
      const char* Bbase = (const char*)Bt + (size_t)i0 * strideB + (size_t)l0 * 2;
      char* AsB = (char*)As;
      char* BsB = (char*)Bs;
      gld16(AsB + wave * 1024,        Abase + (size_t)row0 * strideB + cb);
      gld16(AsB + 4096 + wave * 1024, Abase + (size_t)(row0 + 64) * strideB + cb);
      gld16(BsB + wave * 1024,        Bbase + (size_t)row0 * strideB + cb);
      gld16(BsB + 4096 + wave * 1024, Bbase + (size_t)(row0 + 64) * strideB + cb);
      __syncthreads();

      bf16x8 af[4], bfr[4];
#pragma unroll
      for (int mt = 0; mt < 4; ++mt) {
        int row = wr * 64 + mt * 16 + lo16;
        af[mt] = *reinterpret_cast<const bf16x8*>((const char*)As + row * 64 + hi4 * 16);
      }
#pragma unroll
      for (int nt = 0; nt < 4; ++nt) {
        int row = wc * 64 + nt * 16 + lo16;
        bfr[nt] = *reinterpret_cast<const bf16x8*>((const char*)Bs + row * 64 + hi4 * 16);
      }
#pragma unroll
      for (int mt = 0; mt < 4; ++mt) {
#pragma unroll
        for (int nt = 0; nt < 4; ++nt) {
          acc[mt][nt] = __builtin_amdgcn_mfma_f32_16x16x32_bf16(
              af[mt], bfr[nt], acc[mt][nt], 0, 0, 0);
        }
      }
      __syncthreads();
    }

    // Epilogue: plain stores, out = fe[j] - DT*acc.
#pragma unroll
    for (int mt = 0; mt < 4; ++mt) {
      const int jb = j0 + wr * 64 + mt * 16 + hi4 * 4;
      const float4 fev = *reinterpret_cast<const float4*>(&fe[jb]);
      const float fes[4] = {fev.x, fev.y, fev.z, fev.w};
#pragma unroll
      for (int nt = 0; nt < 4; ++nt) {
        const int i = i0 + wc * 64 + nt * 16 + lo16;
#pragma unroll
        for (int r = 0; r < 4; ++r) {
          out[(size_t)(jb + r) * M + i] = fmaf(-DT, acc[mt][nt][r], fes[r]);
        }
      }
    }
  }
}

extern "C" void kernel_launch(void* const* d_in, const int* in_sizes, int n_in,
                              void* d_out, int out_size, void* d_ws, size_t ws_size,
                              hipStream_t stream) {
  const float* x  = (const float*)d_in[0];
  const float* fe = (const float*)d_in[1];
  const float* h  = (const float*)d_in[2];
  float* out = (float*)d_out;

  const size_t matBytes = (size_t)N * N * sizeof(unsigned short);  // 32 MiB
  if (ws_size < 2 * matBytes) return;

  unsigned short* kbT = (unsigned short*)d_ws;
  unsigned short* Tm  = (unsigned short*)((char*)d_ws + matBytes);

  exp_tr_kernel<<<dim3(M / 64, N / 64), 256, 0, stream>>>(x, kbT);
  build_T_kernel<<<dim3(2, N), 256, 0, stream>>>(h, Tm);
  gemm_tri_kernel<<<dim3(M / BN, 16), 256, 0, stream>>>(Tm, kbT, fe, out);
}

// Round 6
// 203.504 us; speedup vs baseline: 1.7220x; 1.2208x over previous
//
#include <hip/hip_runtime.h>
#include <cstdint>
#include <cstddef>

#define N 4096
#define M 4096
#define DT 0.01f

#define BM 128
#define BN 128
#define BK 64   // K elements staged per barrier pair (2 MFMA half-phases)

typedef short bf16x8 __attribute__((ext_vector_type(8)));
typedef float f32x4 __attribute__((ext_vector_type(4)));

__device__ __forceinline__ unsigned short f2bf(float f) {
  unsigned u = __builtin_bit_cast(unsigned, f);
  return (unsigned short)((u + 0x7fffu + ((u >> 16) & 1u)) >> 16);  // RNE
}

// Fused prep. Blocks [0,4096): exp-transpose tiles -> kbT[i*N+l]=bf16(exp(-x[l*M+i])).
// Blocks [4096,8192): weighted Toeplitz row j: Tm[j*N+l] = w*h[j-l] (l<=j else 0),
// w = 1 + 0.5*[l==j] - 0.5*[l==0]   =>   out = fe[j] - dt*(Tm @ k)[j,i].
__global__ __launch_bounds__(256)
void prep_kernel(const float* __restrict__ x, const float* __restrict__ h,
                 unsigned short* __restrict__ kbT, unsigned short* __restrict__ Tm) {
  __shared__ __align__(16) unsigned short smem[64 * 66];  // 8448 B, both modes
  const int bid = (int)blockIdx.x;
  const int tid = threadIdx.x;

  if (bid < 4096) {
    // ---- exp-transpose 64x64 tile ----
    unsigned short (*tileT)[66] = (unsigned short(*)[66])smem;  // [i][l]
    const int i0 = (bid & 63) * 64, l0 = (bid >> 6) * 64;
    const int ci = (tid & 15) * 4;
    const int r0 = tid >> 4;
#pragma unroll
    for (int rr = 0; rr < 4; ++rr) {
      const int l = l0 + r0 + rr * 16;
      const float4 xv = *reinterpret_cast<const float4*>(&x[(size_t)l * M + i0 + ci]);
      const int lr = r0 + rr * 16;
      tileT[ci + 0][lr] = f2bf(__expf(-xv.x));
      tileT[ci + 1][lr] = f2bf(__expf(-xv.y));
      tileT[ci + 2][lr] = f2bf(__expf(-xv.z));
      tileT[ci + 3][lr] = f2bf(__expf(-xv.w));
    }
    __syncthreads();
    const int ir = tid >> 2, cc = tid & 3;
#pragma unroll
    for (int s = 0; s < 2; ++s) {
      const int ch = cc + s * 4;
      bf16x8 v = *reinterpret_cast<const bf16x8*>(&tileT[ir][ch * 8]);
      *reinterpret_cast<bf16x8*>(&kbT[(size_t)(i0 + ir) * N + l0 + ch * 8]) = v;
    }
  } else {
    // ---- Toeplitz row j: forward-vectorized h load into LDS (bf16), then
    // reversed scalar LDS reads (cheap) + packed stores ----
    const int j = bid - 4096;
    unsigned short* hb = smem;  // hb[0..4095] = bf16(h[.])
#pragma unroll
    for (int p = 0; p < 4; ++p) {
      const int idx = p * 1024 + tid * 4;
      const float4 hv = *reinterpret_cast<const float4*>(&h[idx]);
      ushort4 pk;
      pk.x = f2bf(hv.x); pk.y = f2bf(hv.y); pk.z = f2bf(hv.z); pk.w = f2bf(hv.w);
      *reinterpret_cast<ushort4*>(&hb[idx]) = pk;
    }
    __syncthreads();
    const int l0 = tid * 16;
    unsigned short v[16];
#pragma unroll
    for (int s = 0; s < 16; ++s) {
      const int l = l0 + s;
      unsigned short r = 0;
      if (l <= j) {
        const float w = 1.0f + (l == j ? 0.5f : 0.0f) - (l == 0 ? 0.5f : 0.0f);
        float hv = __builtin_bit_cast(float, (unsigned)hb[j - l] << 16);
        r = f2bf(w * hv);
      }
      v[s] = r;
    }
#pragma unroll
    for (int half = 0; half < 2; ++half) {
      uint4 pk;
      const unsigned short* q = &v[half * 8];
      pk.x = (unsigned)q[0] | ((unsigned)q[1] << 16);
      pk.y = (unsigned)q[2] | ((unsigned)q[3] << 16);
      pk.z = (unsigned)q[4] | ((unsigned)q[5] << 16);
      pk.w = (unsigned)q[6] | ((unsigned)q[7] << 16);
      *reinterpret_cast<uint4*>(&Tm[(size_t)j * N + l0 + half * 8]) = pk;
    }
  }
}

__device__ __forceinline__ void gld16(void* lds, const void* g) {
  __builtin_amdgcn_global_load_lds(
      (const __attribute__((address_space(1))) void*)g,
      (__attribute__((address_space(3))) void*)lds, 16, 0, 0);
}

// Paired triangular GEMM, BK=64 (one barrier pair per 64 K-elements).
// Block (bx,p) owns row-blocks p and 31-p: 66 uniform 64K-iters each.
// LDS tiles 128 rows x 128B with XOR chunk swizzle (conflict-free b128 reads;
// swizzle applied on the GLOBAL source column so global_load_lds stays legal).
__global__ __launch_bounds__(256)
void gemm_tri_kernel(const unsigned short* __restrict__ Tm,
                     const unsigned short* __restrict__ Bt,
                     const float* __restrict__ fe,
                     float* __restrict__ out) {
  __shared__ __align__(16) unsigned short As[BM * BK];  // 16 KB, [row][128B swizzled]
  __shared__ __align__(16) unsigned short Bs[BN * BK];  // 16 KB

  const int tid = threadIdx.x;
  const int wave = tid >> 6, lane = tid & 63;
  const int wr = wave >> 1, wc = wave & 1;
  const int lo16 = lane & 15, hi4 = lane >> 4;
  const int i0 = blockIdx.x * BN;
  const int p = (int)blockIdx.y;
  const int sw = lo16 & 7;  // per-lane read swizzle key (== row&7 for its rows)

  const size_t strideB = (size_t)N * 2;  // 8192 B per matrix row

  // staging: pass pp, chunk c = pp*256+tid; row=c>>3, physchunk=c&7,
  // global chunk = (c&7) ^ (row&7)
  const int srow = tid >> 3;
  const int gq = ((tid & 7) ^ (srow & 7)) * 16;

#pragma unroll 1
  for (int ph = 0; ph < 2; ++ph) {
    const int by = ph ? (31 - p) : p;
    const int j0 = by * BM;
    const int nIter = 2 * by + 2;  // 64K causal bound

    f32x4 acc[4][4] = {};

#pragma unroll 1
    for (int t = 0; t < nIter; ++t) {
      const char* Abase = (const char*)Tm + (size_t)j0 * strideB + (size_t)t * 128;
      const char* Bbase = (const char*)Bt + (size_t)i0 * strideB + (size_t)t * 128;
      char* AsB = (char*)As;
      char* BsB = (char*)Bs;
#pragma unroll
      for (int pp = 0; pp < 4; ++pp) {
        gld16(AsB + pp * 4096 + wave * 1024,
              Abase + (size_t)(srow + pp * 32) * strideB + gq);
        gld16(BsB + pp * 4096 + wave * 1024,
              Bbase + (size_t)(srow + pp * 32) * strideB + gq);
      }
      __syncthreads();

#pragma unroll
      for (int h2 = 0; h2 < 2; ++h2) {
        bf16x8 af[4], bfr[4];
#pragma unroll
        for (int mt = 0; mt < 4; ++mt) {
          const int row = wr * 64 + mt * 16 + lo16;
          const int q = (h2 * 4 + hi4) ^ sw;
          af[mt] = *reinterpret_cast<const bf16x8*>((const char*)As + row * 128 + q * 16);
        }
#pragma unroll
        for (int nt = 0; nt < 4; ++nt) {
          const int row = wc * 64 + nt * 16 + lo16;
          const int q = (h2 * 4 + hi4) ^ sw;
          bfr[nt] = *reinterpret_cast<const bf16x8*>((const char*)Bs + row * 128 + q * 16);
        }
#pragma unroll
        for (int mt = 0; mt < 4; ++mt) {
#pragma unroll
          for (int nt = 0; nt < 4; ++nt) {
            acc[mt][nt] = __builtin_amdgcn_mfma_f32_16x16x32_bf16(
                af[mt], bfr[nt], acc[mt][nt], 0, 0, 0);
          }
        }
      }
      __syncthreads();
    }

    // Epilogue: plain stores, out = fe[j] - DT*acc.
#pragma unroll
    for (int mt = 0; mt < 4; ++mt) {
      const int jb = j0 + wr * 64 + mt * 16 + hi4 * 4;
      const float4 fev = *reinterpret_cast<const float4*>(&fe[jb]);
      const float fes[4] = {fev.x, fev.y, fev.z, fev.w};
#pragma unroll
      for (int nt = 0; nt < 4; ++nt) {
        const int i = i0 + wc * 64 + nt * 16 + lo16;
#pragma unroll
        for (int r = 0; r < 4; ++r) {
          out[(size_t)(jb + r) * M + i] = fmaf(-DT, acc[mt][nt][r], fes[r]);
        }
      }
    }
  }
}

extern "C" void kernel_launch(void* const* d_in, const int* in_sizes, int n_in,
                              void* d_out, int out_size, void* d_ws, size_t ws_size,
                              hipStream_t stream) {
  const float* x  = (const float*)d_in[0];
  const float* fe = (const float*)d_in[1];
  const float* h  = (const float*)d_in[2];
  float* out = (float*)d_out;

  const size_t matBytes = (size_t)N * N * sizeof(unsigned short);  // 32 MiB
  if (ws_size < 2 * matBytes) return;

  unsigned short* kbT = (unsigned short*)d_ws;
  unsigned short* Tm  = (unsigned short*)((char*)d_ws + matBytes);

  prep_kernel<<<8192, 256, 0, stream>>>(x, h, kbT, Tm);
  gemm_tri_kernel<<<dim3(M / BN, 16), 256, 0, stream>>>(Tm, kbT, fe, out);
}

// Round 7
// 184.622 us; speedup vs baseline: 1.8981x; 1.1023x over previous
//
#include <hip/hip_runtime.h>
#include <cstdint>
#include <cstddef>

#define N 4096
#define M 4096
#define DT 0.01f

#define BM 128
#define BN 128
#define BK 64   // K elements staged per barrier pair (2 MFMA half-phases)

typedef short bf16x8 __attribute__((ext_vector_type(8)));
typedef float f32x4 __attribute__((ext_vector_type(4)));

__device__ __forceinline__ unsigned short f2bf(float f) {
  unsigned u = __builtin_bit_cast(unsigned, f);
  return (unsigned short)((u + 0x7fffu + ((u >> 16) & 1u)) >> 16);  // RNE
}

// Fused prep. Blocks [0,4096): exp-transpose tiles -> kbT[i*N+l]=bf16(exp(-x[l*M+i])).
// Blocks [4096,8192): weighted Toeplitz row j: Tm[j*N+l] = w*h[j-l] (l<=j else 0),
// w = 1 + 0.5*[l==j] - 0.5*[l==0]   =>   out = fe[j] - dt*(Tm @ k)[j,i].
__global__ __launch_bounds__(256)
void prep_kernel(const float* __restrict__ x, const float* __restrict__ h,
                 unsigned short* __restrict__ kbT, unsigned short* __restrict__ Tm) {
  __shared__ __align__(16) unsigned short smem[64 * 66];  // 8448 B, both modes
  const int bid = (int)blockIdx.x;
  const int tid = threadIdx.x;

  if (bid < 4096) {
    // ---- exp-transpose 64x64 tile ----
    unsigned short (*tileT)[66] = (unsigned short(*)[66])smem;  // [i][l]
    const int i0 = (bid & 63) * 64, l0 = (bid >> 6) * 64;
    const int ci = (tid & 15) * 4;
    const int r0 = tid >> 4;
#pragma unroll
    for (int rr = 0; rr < 4; ++rr) {
      const int l = l0 + r0 + rr * 16;
      const float4 xv = *reinterpret_cast<const float4*>(&x[(size_t)l * M + i0 + ci]);
      const int lr = r0 + rr * 16;
      tileT[ci + 0][lr] = f2bf(__expf(-xv.x));
      tileT[ci + 1][lr] = f2bf(__expf(-xv.y));
      tileT[ci + 2][lr] = f2bf(__expf(-xv.z));
      tileT[ci + 3][lr] = f2bf(__expf(-xv.w));
    }
    __syncthreads();
    const int ir = tid >> 2, cc = tid & 3;
#pragma unroll
    for (int s = 0; s < 2; ++s) {
      const int ch = cc + s * 4;
      bf16x8 v = *reinterpret_cast<const bf16x8*>(&tileT[ir][ch * 8]);
      *reinterpret_cast<bf16x8*>(&kbT[(size_t)(i0 + ir) * N + l0 + ch * 8]) = v;
    }
  } else {
    // ---- Toeplitz row j ----
    const int j = bid - 4096;
    unsigned short* hb = smem;  // hb[0..4095] = bf16(h[.])
#pragma unroll
    for (int p = 0; p < 4; ++p) {
      const int idx = p * 1024 + tid * 4;
      const float4 hv = *reinterpret_cast<const float4*>(&h[idx]);
      ushort4 pk;
      pk.x = f2bf(hv.x); pk.y = f2bf(hv.y); pk.z = f2bf(hv.z); pk.w = f2bf(hv.w);
      *reinterpret_cast<ushort4*>(&hb[idx]) = pk;
    }
    __syncthreads();
    const int l0 = tid * 16;
    unsigned short v[16];
#pragma unroll
    for (int s = 0; s < 16; ++s) {
      const int l = l0 + s;
      unsigned short r = 0;
      if (l <= j) {
        const float w = 1.0f + (l == j ? 0.5f : 0.0f) - (l == 0 ? 0.5f : 0.0f);
        float hv = __builtin_bit_cast(float, (unsigned)hb[j - l] << 16);
        r = f2bf(w * hv);
      }
      v[s] = r;
    }
#pragma unroll
    for (int half = 0; half < 2; ++half) {
      uint4 pk;
      const unsigned short* q = &v[half * 8];
      pk.x = (unsigned)q[0] | ((unsigned)q[1] << 16);
      pk.y = (unsigned)q[2] | ((unsigned)q[3] << 16);
      pk.z = (unsigned)q[4] | ((unsigned)q[5] << 16);
      pk.w = (unsigned)q[6] | ((unsigned)q[7] << 16);
      *reinterpret_cast<uint4*>(&Tm[(size_t)j * N + l0 + half * 8]) = pk;
    }
  }
}

__device__ __forceinline__ void gld16(void* lds, const void* g) {
  __builtin_amdgcn_global_load_lds(
      (const __attribute__((address_space(1))) void*)g,
      (__attribute__((address_space(3))) void*)lds, 16, 0, 0);
}

// Paired triangular GEMM, BK=64, DOUBLE-BUFFERED LDS with split barriers:
// stage(t+1) is issued BEFORE waiting on tile t; s_waitcnt vmcnt(8) waits only
// the 8 oldest gld16 (tile t), leaving tile t+1's 8 in flight across s_barrier.
// This is the fine-vmcnt K-loop the 2-barrier structure cannot express.
// LDS: As0|As1|Bs0|Bs1, 16 KB each = 64 KB -> still 2 blocks/CU.
__global__ __launch_bounds__(256)
void gemm_tri_kernel(const unsigned short* __restrict__ Tm,
                     const unsigned short* __restrict__ Bt,
                     const float* __restrict__ fe,
                     float* __restrict__ out) {
  __shared__ __align__(16) unsigned short sm[4 * 8192];  // 64 KB

  const int tid = threadIdx.x;
  const int wave = tid >> 6, lane = tid & 63;
  const int wr = wave >> 1, wc = wave & 1;
  const int lo16 = lane & 15, hi4 = lane >> 4;
  const int i0 = blockIdx.x * BN;
  const int p = (int)blockIdx.y;
  const int sw = lo16 & 7;  // read swizzle key (== row&7 for this lane's rows)

  const size_t strideB = (size_t)N * 2;  // 8192 B per matrix row

  // staging: chunk c = pp*256+tid; row=c>>3, phys chunk=c&7, global chunk=(c&7)^(row&7)
  const int srow = tid >> 3;
  const int gq = ((tid & 7) ^ (srow & 7)) * 16;

  // 8 gld16 per wave per stage: A (4 passes) + B (4 passes) interleaved
  auto stage = [&](int j0s, int t, int buf) {
    const char* Abase = (const char*)Tm + (size_t)j0s * strideB + (size_t)t * 128;
    const char* Bbase = (const char*)Bt + (size_t)i0 * strideB + (size_t)t * 128;
    char* AsB = (char*)sm + buf * 16384;
    char* BsB = (char*)sm + 32768 + buf * 16384;
#pragma unroll
    for (int pp = 0; pp < 4; ++pp) {
      gld16(AsB + pp * 4096 + wave * 1024,
            Abase + (size_t)(srow + pp * 32) * strideB + gq);
      gld16(BsB + pp * 4096 + wave * 1024,
            Bbase + (size_t)(srow + pp * 32) * strideB + gq);
    }
  };

#pragma unroll 1
  for (int ph = 0; ph < 2; ++ph) {
    const int by = ph ? (31 - p) : p;
    const int j0 = by * BM;
    const int nIter = 2 * by + 2;  // 64K causal bound

    f32x4 acc[4][4] = {};

    stage(j0, 0, 0);  // prologue

#pragma unroll 1
    for (int t = 0; t < nIter; ++t) {
      const int cur = t & 1;
      if (t + 1 < nIter) {
        stage(j0, t + 1, cur ^ 1);
        asm volatile("s_waitcnt vmcnt(8)" ::: "memory");  // tile t landed; t+1 in flight
      } else {
        asm volatile("s_waitcnt vmcnt(0)" ::: "memory");  // last tile: full drain
      }
      __builtin_amdgcn_s_barrier();

      const char* AsC = (const char*)sm + cur * 16384;
      const char* BsC = (const char*)sm + 32768 + cur * 16384;
#pragma unroll
      for (int h2 = 0; h2 < 2; ++h2) {
        bf16x8 af[4], bfr[4];
#pragma unroll
        for (int mt = 0; mt < 4; ++mt) {
          const int row = wr * 64 + mt * 16 + lo16;
          const int q = (h2 * 4 + hi4) ^ sw;
          af[mt] = *reinterpret_cast<const bf16x8*>(AsC + row * 128 + q * 16);
        }
#pragma unroll
        for (int nt = 0; nt < 4; ++nt) {
          const int row = wc * 64 + nt * 16 + lo16;
          const int q = (h2 * 4 + hi4) ^ sw;
          bfr[nt] = *reinterpret_cast<const bf16x8*>(BsC + row * 128 + q * 16);
        }
#pragma unroll
        for (int mt = 0; mt < 4; ++mt) {
#pragma unroll
          for (int nt = 0; nt < 4; ++nt) {
            acc[mt][nt] = __builtin_amdgcn_mfma_f32_16x16x32_bf16(
                af[mt], bfr[nt], acc[mt][nt], 0, 0, 0);
          }
        }
      }
      __builtin_amdgcn_s_barrier();  // all reads of buf `cur` done before next overwrite
    }

    // Epilogue: plain stores, out = fe[j] - DT*acc.
#pragma unroll
    for (int mt = 0; mt < 4; ++mt) {
      const int jb = j0 + wr * 64 + mt * 16 + hi4 * 4;
      const float4 fev = *reinterpret_cast<const float4*>(&fe[jb]);
      const float fes[4] = {fev.x, fev.y, fev.z, fev.w};
#pragma unroll
      for (int nt = 0; nt < 4; ++nt) {
        const int i = i0 + wc * 64 + nt * 16 + lo16;
#pragma unroll
        for (int r = 0; r < 4; ++r) {
          out[(size_t)(jb + r) * M + i] = fmaf(-DT, acc[mt][nt][r], fes[r]);
        }
      }
    }
  }
}

extern "C" void kernel_launch(void* const* d_in, const int* in_sizes, int n_in,
                              void* d_out, int out_size, void* d_ws, size_t ws_size,
                              hipStream_t stream) {
  const float* x  = (const float*)d_in[0];
  const float* fe = (const float*)d_in[1];
  const float* h  = (const float*)d_in[2];
  float* out = (float*)d_out;

  const size_t matBytes = (size_t)N * N * sizeof(unsigned short);  // 32 MiB
  if (ws_size < 2 * matBytes) return;

  unsigned short* kbT = (unsigned short*)d_ws;
  unsigned short* Tm  = (unsigned short*)((char*)d_ws + matBytes);

  prep_kernel<<<8192, 256, 0, stream>>>(x, h, kbT, Tm);
  gemm_tri_kernel<<<dim3(M / BN, 16), 256, 0, stream>>>(Tm, kbT, fe, out);
}